// Round 1
// baseline (440.811 us; speedup 1.0000x reference)
//
#include <hip/hip_runtime.h>

// STS linear attention, fp32.
// Shapes: B=4, N=4096, H=8, D=64, M=64.  out[b,n,h,m].
// Phase 1: KV[bh][m][d] = sum_n f(K)[n,d]*V[n,m];  Ksum[bh][d] = sum_n f(K)[n,d]   (atomics into ws)
// Phase 2: out[n,m] = (sum_d f(Q)[n,d]*KV[m,d]) * 1/(sum_d f(Q)[n,d]*Ksum[d] + eps)

#define EPSC 1e-6f

constexpr int Bq = 4;
constexpr int Nq = 4096;
constexpr int Hq = 8;
constexpr int Dq = 64;
constexpr int Mq = 64;
constexpr int BH = Bq * Hq;          // 32
constexpr int RSTR = Hq * Dq;        // 512 floats between consecutive n

__device__ __forceinline__ float fmap(float x) {
    // elu(x) + 1
    return x > 0.0f ? x + 1.0f : __expf(x);
}

// ---------------- Phase 1: KV + Ksum reduction ----------------
constexpr int NC1 = 64;              // n-rows per (1-wave) block

__global__ __launch_bounds__(64)
void phase1_kv(const float* __restrict__ Kp, const float* __restrict__ Vp,
               float* __restrict__ wsKV, float* __restrict__ wsKS)
{
    constexpr int CH = Nq / NC1;     // 64 chunks per (b,h)
    const int bh = blockIdx.x / CH;
    const int ck = blockIdx.x - bh * CH;
    const int b  = bh >> 3;
    const int h  = bh & 7;
    const int lane = threadIdx.x;
    const int dg = lane & 7;         // d-tile: d = dg*8 + di
    const int mg = lane >> 3;        // m-tile: m = mg*8 + mi

    const float* Kb = Kp + (size_t)(b * Nq + ck * NC1) * RSTR + h * Dq;
    const float* Vb = Vp + (size_t)(b * Nq + ck * NC1) * RSTR + h * Dq;

    float acc[8][8];                 // [mi][di]
    #pragma unroll
    for (int i = 0; i < 8; ++i)
        #pragma unroll
        for (int j = 0; j < 8; ++j) acc[i][j] = 0.0f;
    float ksum[8] = {0.f,0.f,0.f,0.f,0.f,0.f,0.f,0.f};

    #pragma unroll 2
    for (int n0 = 0; n0 < NC1; n0 += 4) {
        float4 kA[4], kB[4], vA[4], vB[4];
        #pragma unroll
        for (int u = 0; u < 4; ++u) {
            const float* kr = Kb + (size_t)(n0 + u) * RSTR;
            const float* vr = Vb + (size_t)(n0 + u) * RSTR;
            kA[u] = *(const float4*)(kr + dg * 8);
            kB[u] = *(const float4*)(kr + dg * 8 + 4);
            vA[u] = *(const float4*)(vr + mg * 8);
            vB[u] = *(const float4*)(vr + mg * 8 + 4);
        }
        #pragma unroll
        for (int u = 0; u < 4; ++u) {
            float kf[8], vf[8];
            kf[0] = fmap(kA[u].x); kf[1] = fmap(kA[u].y); kf[2] = fmap(kA[u].z); kf[3] = fmap(kA[u].w);
            kf[4] = fmap(kB[u].x); kf[5] = fmap(kB[u].y); kf[6] = fmap(kB[u].z); kf[7] = fmap(kB[u].w);
            vf[0] = vA[u].x; vf[1] = vA[u].y; vf[2] = vA[u].z; vf[3] = vA[u].w;
            vf[4] = vB[u].x; vf[5] = vB[u].y; vf[6] = vB[u].z; vf[7] = vB[u].w;
            #pragma unroll
            for (int mi = 0; mi < 8; ++mi)
                #pragma unroll
                for (int di = 0; di < 8; ++di)
                    acc[mi][di] = fmaf(vf[mi], kf[di], acc[mi][di]);
            if (mg == 0) {
                #pragma unroll
                for (int di = 0; di < 8; ++di) ksum[di] += kf[di];
            }
        }
    }

    float* dst = wsKV + (size_t)bh * Mq * Dq;
    #pragma unroll
    for (int mi = 0; mi < 8; ++mi) {
        const int m = mg * 8 + mi;
        #pragma unroll
        for (int di = 0; di < 8; ++di) {
            atomicAdd(&dst[m * Dq + dg * 8 + di], acc[mi][di]);
        }
    }
    if (mg == 0) {
        #pragma unroll
        for (int di = 0; di < 8; ++di)
            atomicAdd(&wsKS[bh * Dq + dg * 8 + di], ksum[di]);
    }
}

// ---------------- Phase 2: out = f(Q) @ KV^T, normalized ----------------
constexpr int RC2 = 256;             // rows per 256-thread block

__global__ __launch_bounds__(256, 2)
void phase2_out(const float* __restrict__ Qp, const float* __restrict__ wsKV,
                const float* __restrict__ wsKS, float* __restrict__ Out)
{
    constexpr int CH = Nq / RC2;     // 16 chunks per (b,h)
    const int bh = blockIdx.x / CH;
    const int ck = blockIdx.x - bh * CH;
    const int b  = bh >> 3;
    const int h  = bh & 7;

    __shared__ float sKV[Mq * 68];   // stride 68 floats (16B-aligned rows, bank-spread via strided-m read)
    __shared__ float sKS[Dq];

    const int tid = threadIdx.x;
    const float* kvsrc = wsKV + (size_t)bh * Mq * Dq;
    #pragma unroll
    for (int it = 0; it < 4; ++it) {
        const int flat = tid * 4 + it * 1024;
        const int m = flat >> 6, d = flat & 63;
        *(float4*)&sKV[m * 68 + d] = *(const float4*)(kvsrc + flat);
    }
    if (tid < 16) {
        *(float4*)&sKS[tid * 4] = *(const float4*)(wsKS + bh * Dq + tid * 4);
    }
    __syncthreads();

    const int mg = tid & 7;          // m = mg + 8*mi (strided -> conflict-free LDS reads)
    const int rg = tid >> 3;         // 0..31
    const int row0 = ck * RC2 + rg * 8;
    const float* Qb = Qp + (size_t)(b * Nq + row0) * RSTR + h * Dq;

    float acc[8][8];                 // [i(row)][mi]
    float zac[8];
    #pragma unroll
    for (int i = 0; i < 8; ++i) {
        zac[i] = 0.0f;
        #pragma unroll
        for (int j = 0; j < 8; ++j) acc[i][j] = 0.0f;
    }

    #pragma unroll 2
    for (int d4 = 0; d4 < 16; ++d4) {
        const float4 ks4 = *(const float4*)&sKS[d4 * 4];
        float qf[8][4];
        #pragma unroll
        for (int i = 0; i < 8; ++i) {
            const float4 q = *(const float4*)(Qb + (size_t)i * RSTR + d4 * 4);
            qf[i][0] = fmap(q.x); qf[i][1] = fmap(q.y);
            qf[i][2] = fmap(q.z); qf[i][3] = fmap(q.w);
            zac[i] = fmaf(qf[i][0], ks4.x, zac[i]);
            zac[i] = fmaf(qf[i][1], ks4.y, zac[i]);
            zac[i] = fmaf(qf[i][2], ks4.z, zac[i]);
            zac[i] = fmaf(qf[i][3], ks4.w, zac[i]);
        }
        #pragma unroll
        for (int mi = 0; mi < 8; ++mi) {
            const float4 kv4 = *(const float4*)&sKV[(mg + 8 * mi) * 68 + d4 * 4];
            #pragma unroll
            for (int i = 0; i < 8; ++i) {
                acc[i][mi] = fmaf(qf[i][0], kv4.x, acc[i][mi]);
                acc[i][mi] = fmaf(qf[i][1], kv4.y, acc[i][mi]);
                acc[i][mi] = fmaf(qf[i][2], kv4.z, acc[i][mi]);
                acc[i][mi] = fmaf(qf[i][3], kv4.w, acc[i][mi]);
            }
        }
    }

    float* Ob = Out + (size_t)(b * Nq + row0) * RSTR + h * Mq;
    #pragma unroll
    for (int i = 0; i < 8; ++i) {
        const float z = 1.0f / (zac[i] + EPSC);
        #pragma unroll
        for (int mi = 0; mi < 8; ++mi)
            Ob[(size_t)i * RSTR + mg + 8 * mi] = acc[i][mi] * z;
    }
}

extern "C" void kernel_launch(void* const* d_in, const int* in_sizes, int n_in,
                              void* d_out, int out_size, void* d_ws, size_t ws_size,
                              hipStream_t stream)
{
    (void)in_sizes; (void)n_in; (void)out_size; (void)ws_size;
    const float* Q = (const float*)d_in[0];
    const float* K = (const float*)d_in[1];
    const float* V = (const float*)d_in[2];
    // d_in[3] = attn_mask (dummy, ignored)
    float* out = (float*)d_out;

    float* wsKV = (float*)d_ws;                       // [BH][M][D]   = 512 KB
    float* wsKS = wsKV + (size_t)BH * Mq * Dq;        // [BH][D]      = 8 KB
    const size_t zbytes = (size_t)(BH * Mq * Dq + BH * Dq) * sizeof(float);
    hipMemsetAsync(d_ws, 0, zbytes, stream);

    phase1_kv<<<BH * (Nq / NC1), 64, 0, stream>>>(K, V, wsKV, wsKS);
    phase2_out<<<BH * (Nq / RC2), 256, 0, stream>>>(Q, wsKV, wsKS, out);
}

// Round 2
// 243.630 us; speedup vs baseline: 1.8093x; 1.8093x over previous
//
#include <hip/hip_runtime.h>

// STS linear attention, fp32.  B=4, N=4096, H=8, D=64, M=64.
// phase1 : per-wave partial KV tiles (64x64) + Ksum partials, NO atomics.
//          Partial KV tiles (32 MB) live in d_out (overwritten by phase2 later).
// phase1b: reduce 64 partials per (b,h) -> final KV [32][64][64], Ksum [32][64] in d_ws.
// phase2 : out[n,m] = (sum_d f(Q)[n,d]*KV[m,d]) / (sum_d f(Q)[n,d]*Ksum[d] + eps)

#define EPSC 1e-6f

constexpr int Bq = 4;
constexpr int Nq = 4096;
constexpr int Hq = 8;
constexpr int Dq = 64;
constexpr int Mq = 64;
constexpr int BH = Bq * Hq;          // 32
constexpr int RSTR = Hq * Dq;        // 512 floats between consecutive n
constexpr int TILESZ = Mq * Dq;      // 4096 floats per partial tile

__device__ __forceinline__ float fmap(float x) {
    return x > 0.0f ? x + 1.0f : __expf(x);   // elu(x)+1
}

// ---------------- Phase 1: per-wave partial KV tiles ----------------
// grid = BH*16 blocks, 256 threads (4 waves). Each wave: 64 rows -> one 64x64 tile.
__global__ __launch_bounds__(256)
void phase1_kv(const float* __restrict__ Kp, const float* __restrict__ Vp,
               float* __restrict__ partKV, float* __restrict__ partKS)
{
    const int wid  = threadIdx.x >> 6;            // wave in block: 0..3
    const int lane = threadIdx.x & 63;
    const int tile = blockIdx.x * 4 + wid;        // 0..2047
    const int bh = blockIdx.x >> 4;               // 16 blocks per bh
    const int ck = blockIdx.x & 15;
    const int b  = bh >> 3;
    const int h  = bh & 7;
    const int dg = lane & 7;                      // d = dg*8 + di
    const int mg = lane >> 3;                     // m = mg*8 + mi
    const int n0base = ck * 256 + wid * 64;       // 64 rows per wave

    const float* Kb = Kp + (size_t)(b * Nq + n0base) * RSTR + h * Dq;
    const float* Vb = Vp + (size_t)(b * Nq + n0base) * RSTR + h * Dq;

    float acc[8][8];                              // [mi][di]
    #pragma unroll
    for (int i = 0; i < 8; ++i)
        #pragma unroll
        for (int j = 0; j < 8; ++j) acc[i][j] = 0.0f;
    float ksum[8] = {0.f,0.f,0.f,0.f,0.f,0.f,0.f,0.f};

    #pragma unroll 2
    for (int n0 = 0; n0 < 64; n0 += 4) {
        float4 kA[4], kB[4], vA[4], vB[4];
        #pragma unroll
        for (int u = 0; u < 4; ++u) {
            const float* kr = Kb + (size_t)(n0 + u) * RSTR;
            const float* vr = Vb + (size_t)(n0 + u) * RSTR;
            kA[u] = *(const float4*)(kr + dg * 8);
            kB[u] = *(const float4*)(kr + dg * 8 + 4);
            vA[u] = *(const float4*)(vr + mg * 8);
            vB[u] = *(const float4*)(vr + mg * 8 + 4);
        }
        #pragma unroll
        for (int u = 0; u < 4; ++u) {
            float kf[8], vf[8];
            kf[0] = fmap(kA[u].x); kf[1] = fmap(kA[u].y); kf[2] = fmap(kA[u].z); kf[3] = fmap(kA[u].w);
            kf[4] = fmap(kB[u].x); kf[5] = fmap(kB[u].y); kf[6] = fmap(kB[u].z); kf[7] = fmap(kB[u].w);
            vf[0] = vA[u].x; vf[1] = vA[u].y; vf[2] = vA[u].z; vf[3] = vA[u].w;
            vf[4] = vB[u].x; vf[5] = vB[u].y; vf[6] = vB[u].z; vf[7] = vB[u].w;
            #pragma unroll
            for (int mi = 0; mi < 8; ++mi)
                #pragma unroll
                for (int di = 0; di < 8; ++di)
                    acc[mi][di] = fmaf(vf[mi], kf[di], acc[mi][di]);
            if (mg == 0) {
                #pragma unroll
                for (int di = 0; di < 8; ++di) ksum[di] += kf[di];
            }
        }
    }

    // coalesced float4 stores of this wave's private tile
    float* dst = partKV + (size_t)tile * TILESZ;
    #pragma unroll
    for (int mi = 0; mi < 8; ++mi) {
        const int m = mg * 8 + mi;
        float4 a0 = make_float4(acc[mi][0], acc[mi][1], acc[mi][2], acc[mi][3]);
        float4 a1 = make_float4(acc[mi][4], acc[mi][5], acc[mi][6], acc[mi][7]);
        *(float4*)&dst[m * Dq + dg * 8]     = a0;
        *(float4*)&dst[m * Dq + dg * 8 + 4] = a1;
    }
    if (mg == 0) {
        float* kd = partKS + (size_t)tile * Dq + dg * 8;
        *(float4*)&kd[0] = make_float4(ksum[0], ksum[1], ksum[2], ksum[3]);
        *(float4*)&kd[4] = make_float4(ksum[4], ksum[5], ksum[6], ksum[7]);
    }
}

// ---------------- Phase 1b: reduce 64 partials per bh ----------------
// grid = BH*4 blocks, 256 threads. Each thread: one float4 of the output tile.
__global__ __launch_bounds__(256)
void phase1b_reduce(const float* __restrict__ partKV, const float* __restrict__ partKS,
                    float* __restrict__ KV, float* __restrict__ KS)
{
    const int bh = blockIdx.x >> 2;
    const int q  = blockIdx.x & 3;
    const int t  = threadIdx.x;
    const int off = q * 1024 + t * 4;
    const float* src = partKV + (size_t)bh * 64 * TILESZ;

    float4 a = make_float4(0.f, 0.f, 0.f, 0.f);
    #pragma unroll 8
    for (int p = 0; p < 64; ++p) {
        float4 v = *(const float4*)(src + (size_t)p * TILESZ + off);
        a.x += v.x; a.y += v.y; a.z += v.z; a.w += v.w;
    }
    *(float4*)&KV[(size_t)bh * TILESZ + off] = a;

    if (q == 0 && t < Dq) {
        const float* ks = partKS + (size_t)bh * 64 * Dq;
        float s = 0.0f;
        #pragma unroll 8
        for (int p = 0; p < 64; ++p) s += ks[p * Dq + t];
        KS[bh * Dq + t] = s;
    }
}

// ---------------- Phase 2: out = f(Q) @ KV^T, normalized ----------------
constexpr int RC2 = 256;             // rows per 256-thread block

__global__ __launch_bounds__(256, 2)
void phase2_out(const float* __restrict__ Qp, const float* __restrict__ wsKV,
                const float* __restrict__ wsKS, float* __restrict__ Out)
{
    constexpr int CH = Nq / RC2;     // 16 chunks per (b,h)
    const int bh = blockIdx.x / CH;
    const int ck = blockIdx.x - bh * CH;
    const int b  = bh >> 3;
    const int h  = bh & 7;

    __shared__ float sKV[Mq * 68];   // stride 68 floats; strided-m read -> conflict-free
    __shared__ float sKS[Dq];

    const int tid = threadIdx.x;
    const float* kvsrc = wsKV + (size_t)bh * TILESZ;
    #pragma unroll
    for (int it = 0; it < 4; ++it) {
        const int flat = tid * 4 + it * 1024;
        const int m = flat >> 6, d = flat & 63;
        *(float4*)&sKV[m * 68 + d] = *(const float4*)(kvsrc + flat);
    }
    if (tid < 16) {
        *(float4*)&sKS[tid * 4] = *(const float4*)(wsKS + bh * Dq + tid * 4);
    }
    __syncthreads();

    const int mg = tid & 7;          // m = mg + 8*mi
    const int rg = tid >> 3;         // 0..31
    const int row0 = ck * RC2 + rg * 8;
    const float* Qb = Qp + (size_t)(b * Nq + row0) * RSTR + h * Dq;

    float acc[8][8];                 // [i(row)][mi]
    float zac[8];
    #pragma unroll
    for (int i = 0; i < 8; ++i) {
        zac[i] = 0.0f;
        #pragma unroll
        for (int j = 0; j < 8; ++j) acc[i][j] = 0.0f;
    }

    #pragma unroll 2
    for (int d4 = 0; d4 < 16; ++d4) {
        const float4 ks4 = *(const float4*)&sKS[d4 * 4];
        float qf[8][4];
        #pragma unroll
        for (int i = 0; i < 8; ++i) {
            const float4 q = *(const float4*)(Qb + (size_t)i * RSTR + d4 * 4);
            qf[i][0] = fmap(q.x); qf[i][1] = fmap(q.y);
            qf[i][2] = fmap(q.z); qf[i][3] = fmap(q.w);
            zac[i] = fmaf(qf[i][0], ks4.x, zac[i]);
            zac[i] = fmaf(qf[i][1], ks4.y, zac[i]);
            zac[i] = fmaf(qf[i][2], ks4.z, zac[i]);
            zac[i] = fmaf(qf[i][3], ks4.w, zac[i]);
        }
        #pragma unroll
        for (int mi = 0; mi < 8; ++mi) {
            const float4 kv4 = *(const float4*)&sKV[(mg + 8 * mi) * 68 + d4 * 4];
            #pragma unroll
            for (int i = 0; i < 8; ++i) {
                acc[i][mi] = fmaf(qf[i][0], kv4.x, acc[i][mi]);
                acc[i][mi] = fmaf(qf[i][1], kv4.y, acc[i][mi]);
                acc[i][mi] = fmaf(qf[i][2], kv4.z, acc[i][mi]);
                acc[i][mi] = fmaf(qf[i][3], kv4.w, acc[i][mi]);
            }
        }
    }

    float* Ob = Out + (size_t)(b * Nq + row0) * RSTR + h * Mq;
    #pragma unroll
    for (int i = 0; i < 8; ++i) {
        const float z = 1.0f / (zac[i] + EPSC);
        #pragma unroll
        for (int mi = 0; mi < 8; ++mi)
            Ob[(size_t)i * RSTR + mg + 8 * mi] = acc[i][mi] * z;
    }
}

extern "C" void kernel_launch(void* const* d_in, const int* in_sizes, int n_in,
                              void* d_out, int out_size, void* d_ws, size_t ws_size,
                              hipStream_t stream)
{
    (void)in_sizes; (void)n_in; (void)out_size; (void)ws_size;
    const float* Q = (const float*)d_in[0];
    const float* K = (const float*)d_in[1];
    const float* V = (const float*)d_in[2];
    float* out = (float*)d_out;

    // d_out doubles as scratch for the 2048 partial KV tiles (exactly out_size floats);
    // phase2 overwrites it with the final result.
    float* partKV = out;                                   // [2048][4096] = 32 MB
    float* wsKV   = (float*)d_ws;                          // [32][4096]   = 512 KB
    float* wsKS   = wsKV + (size_t)BH * TILESZ;            // [32][64]     = 8 KB
    float* partKS = wsKS + (size_t)BH * Dq;                // [2048][64]   = 512 KB

    phase1_kv<<<BH * 16, 256, 0, stream>>>(K, V, partKV, partKS);
    phase1b_reduce<<<BH * 4, 256, 0, stream>>>(partKV, partKS, wsKV, wsKS);
    phase2_out<<<BH * (Nq / RC2), 256, 0, stream>>>(Q, wsKV, wsKS, out);
}